// Round 9
// baseline (229.775 us; speedup 1.0000x reference)
//
#include <hip/hip_runtime.h>

// ---------------------------------------------------------------------------
// LSH attention, MI355X.  B=2, S=2048, E=1024, H=16, Dh=64, NB=64, NH=6.
// ALL inputs/outputs are FP32.
//   0) split_kernel: fp32 -> bf16 hi (+ optional lo residual)
//   1) gemm_qv v2: 1024 blocks (4/CU — round-8 evidence: at 2 blocks/CU the
//      kernel ran ~95us vs ~35us pipe-max, i.e. zero overlap; compiler's
//      vmcnt(0)-before-barrier makes dbuf useless, so TLP is the only fix).
//      64x128 tiles, BK=32.  LDS row stride 64B -> fragment reads spread
//      evenly over all 8 16B bank groups with NO swizzle.
//   2) bucket_kernel: bucket bits = sign(fp32 q . hyperplanes) + row |q|^2
//   3) attn_kernel v6 (unchanged from round 8: 100.8us, FETCH 12.6MB).
// ---------------------------------------------------------------------------

typedef short short8 __attribute__((ext_vector_type(8)));
typedef float f32x4 __attribute__((ext_vector_type(4)));
typedef unsigned short us4 __attribute__((ext_vector_type(4)));

__device__ __forceinline__ float bff(unsigned short h) {
    return __uint_as_float(((unsigned int)h) << 16);
}
__device__ __forceinline__ unsigned short f2bf(float f) {  // RNE, finite inputs
    unsigned int u = __float_as_uint(f);
    u += 0x7fffu + ((u >> 16) & 1u);
    return (unsigned short)(u >> 16);
}

__device__ __forceinline__ void glds16(const unsigned short* g, unsigned short* l) {
    __builtin_amdgcn_global_load_lds(
        (const __attribute__((address_space(1))) unsigned int*)g,
        (__attribute__((address_space(3))) unsigned int*)l, 16, 0, 0);
}

// ---------------------------------------------------------------------------
__global__ __launch_bounds__(256) void split_kernel(
    const float* __restrict__ in, unsigned short* __restrict__ hi,
    unsigned short* __restrict__ lo, int n4)
{
    const int idx = blockIdx.x * 256 + threadIdx.x;
    if (idx >= n4) return;
    const float4 v = ((const float4*)in)[idx];
    us4 h;
    h.x = f2bf(v.x); h.y = f2bf(v.y); h.z = f2bf(v.z); h.w = f2bf(v.w);
    ((us4*)hi)[idx] = h;
    if (lo) {
        us4 l;
        l.x = f2bf(v.x - bff(h.x)); l.y = f2bf(v.y - bff(h.y));
        l.z = f2bf(v.z - bff(h.z)); l.w = f2bf(v.w - bff(h.w));
        ((us4*)lo)[idx] = l;
    }
}

// ---------------------------------------------------------------------------
// Merged projection GEMM v2.  Grid 1024 = 4 blocks/CU.
//   blk <  512: Q path.  64x128 tile: m0=(blk>>3)*64 tokens, n0=(blk&7)*128
//               channels.  3-term hi/lo.
//   blk >= 512: V path.  64x128 tile: m0 channels, n0 tokens.  1-term.
// BK=32 (one 16x16x32 k-step per iter), 32 iters.  LDS 24 KB, no swizzle
// (64B row stride spreads fragment reads over all 8 bank groups).
// Staging: one glds16 call = 16 rows x 32k (lane>>2 = row, lane&3 = chunk).
// ---------------------------------------------------------------------------
__global__ __launch_bounds__(256, 4) void gemm_qv(
    const unsigned short* __restrict__ xh, const unsigned short* __restrict__ xl,
    const unsigned short* __restrict__ wqh, const unsigned short* __restrict__ wql,
    const unsigned short* __restrict__ wvh,
    const float* __restrict__ bq, const float* __restrict__ bv,
    float* __restrict__ Qf, unsigned short* __restrict__ Qb,
    unsigned short* __restrict__ Qlo, unsigned short* __restrict__ Vt)
{
    __shared__ unsigned short Ah[64 * 32], Al[64 * 32];
    __shared__ unsigned short Bh[128 * 32], Bl[128 * 32];

    const int tid = threadIdx.x;
    const int w = tid >> 6, lane = tid & 63;
    const int i = lane & 15, qd = lane >> 4;
    const int srow = lane >> 2, schk = (lane & 3) * 8;  // staging row/chunk
    const int nw = w * 32;
    const int blk = blockIdx.x;
    const bool isq = blk < 512;

    f32x4 acc[4][2];
#pragma unroll
    for (int a = 0; a < 4; ++a)
#pragma unroll
        for (int b2 = 0; b2 < 2; ++b2) acc[a][b2] = f32x4{0.f, 0.f, 0.f, 0.f};

    if (isq) {
        const int m0 = (blk >> 3) * 64;    // token tile (64 rows)
        const int n0 = (blk & 7) * 128;    // channel tile (128 cols)
        for (int k0 = 0; k0 < 1024; k0 += 32) {
            __syncthreads();
            // 24 staging calls: Ah 0-3, Al 4-7, Bh 8-15, Bl 16-23; wave w
            // takes calls w*6..w*6+5.
#pragma unroll
            for (int cc = 0; cc < 6; ++cc) {
                const int c = w * 6 + cc;
                if (c < 4) {
                    const int rb = c * 16;
                    glds16(xh + (size_t)(m0 + rb + srow) * 1024 + k0 + schk,
                           &Ah[rb * 32]);
                } else if (c < 8) {
                    const int rb = (c - 4) * 16;
                    glds16(xl + (size_t)(m0 + rb + srow) * 1024 + k0 + schk,
                           &Al[rb * 32]);
                } else if (c < 16) {
                    const int rb = (c - 8) * 16;
                    glds16(wqh + (size_t)(n0 + rb + srow) * 1024 + k0 + schk,
                           &Bh[rb * 32]);
                } else {
                    const int rb = (c - 16) * 16;
                    glds16(wql + (size_t)(n0 + rb + srow) * 1024 + k0 + schk,
                           &Bl[rb * 32]);
                }
            }
            __syncthreads();

            short8 ah[4], al[4], bh2[2], bl2[2];
#pragma unroll
            for (int mm = 0; mm < 4; ++mm) {
                ah[mm] = *(const short8*)&Ah[(mm * 16 + i) * 32 + qd * 8];
                al[mm] = *(const short8*)&Al[(mm * 16 + i) * 32 + qd * 8];
            }
#pragma unroll
            for (int nn = 0; nn < 2; ++nn) {
                bh2[nn] = *(const short8*)&Bh[(nw + nn * 16 + i) * 32 + qd * 8];
                bl2[nn] = *(const short8*)&Bl[(nw + nn * 16 + i) * 32 + qd * 8];
            }
#pragma unroll
            for (int mm = 0; mm < 4; ++mm)
#pragma unroll
                for (int nn = 0; nn < 2; ++nn) {
                    acc[mm][nn] = __builtin_amdgcn_mfma_f32_16x16x32_bf16(
                        ah[mm], bh2[nn], acc[mm][nn], 0, 0, 0);
                    acc[mm][nn] = __builtin_amdgcn_mfma_f32_16x16x32_bf16(
                        al[mm], bh2[nn], acc[mm][nn], 0, 0, 0);
                    acc[mm][nn] = __builtin_amdgcn_mfma_f32_16x16x32_bf16(
                        ah[mm], bl2[nn], acc[mm][nn], 0, 0, 0);
                }
        }
        // epilogue: C layout col=i, row=qd*4+reg [m89]
#pragma unroll
        for (int mm = 0; mm < 4; ++mm)
#pragma unroll
            for (int nn = 0; nn < 2; ++nn)
#pragma unroll
                for (int rr = 0; rr < 4; ++rr) {
                    const int row = m0 + mm * 16 + qd * 4 + rr;  // token
                    const int col = n0 + nw + nn * 16 + i;       // channel
                    const float v = acc[mm][nn][rr] + bq[col];
                    Qf[(size_t)row * 1024 + col] = v;
                    const unsigned short hs = f2bf(v);
                    const float lo = v - bff(hs);
                    const int b = row >> 11, s = row & 2047;
                    const int hh = col >> 6, d = col & 63;
                    const size_t oi = ((size_t)((b << 4) + hh) * 2048 + s) * 64 + d;
                    Qb[oi] = hs;
                    Qlo[oi] = f2bf(lo);
                }
    } else {
        const int b2 = blk - 512;
        const int m0 = (b2 >> 5) * 64;     // channel tile (64 rows)
        const int n0 = (b2 & 31) * 128;    // token tile (128 cols)
        for (int k0 = 0; k0 < 1024; k0 += 32) {
            __syncthreads();
            // 12 staging calls: Ah 0-3, Bh 4-11; wave w takes calls w*3..w*3+2
#pragma unroll
            for (int cc = 0; cc < 3; ++cc) {
                const int c = w * 3 + cc;
                if (c < 4) {
                    const int rb = c * 16;
                    glds16(wvh + (size_t)(m0 + rb + srow) * 1024 + k0 + schk,
                           &Ah[rb * 32]);
                } else {
                    const int rb = (c - 4) * 16;
                    glds16(xh + (size_t)(n0 + rb + srow) * 1024 + k0 + schk,
                           &Bh[rb * 32]);
                }
            }
            __syncthreads();

            short8 af[4], bf2[2];
#pragma unroll
            for (int mm = 0; mm < 4; ++mm)
                af[mm] = *(const short8*)&Ah[(mm * 16 + i) * 32 + qd * 8];
#pragma unroll
            for (int nn = 0; nn < 2; ++nn)
                bf2[nn] = *(const short8*)&Bh[(nw + nn * 16 + i) * 32 + qd * 8];
#pragma unroll
            for (int mm = 0; mm < 4; ++mm)
#pragma unroll
                for (int nn = 0; nn < 2; ++nn)
                    acc[mm][nn] = __builtin_amdgcn_mfma_f32_16x16x32_bf16(
                        af[mm], bf2[nn], acc[mm][nn], 0, 0, 0);
        }
#pragma unroll
        for (int mm = 0; mm < 4; ++mm)
#pragma unroll
            for (int nn = 0; nn < 2; ++nn)
#pragma unroll
                for (int rr = 0; rr < 4; ++rr) {
                    const int rch = m0 + mm * 16 + qd * 4 + rr;  // channel
                    const int tok = n0 + nw + nn * 16 + i;       // token
                    const float v = acc[mm][nn][rr] + bv[rch];
                    const int b = tok >> 11, s = tok & 2047;
                    Vt[((size_t)(b * 1024 + rch)) * 2048 + s] = f2bf(v);
                }
    }
}

// ---------------------------------------------------------------------------
// Buckets + row norms from fp32 q.  One thread per (token, head), float4.
// ---------------------------------------------------------------------------
__global__ __launch_bounds__(256) void bucket_kernel(
    const float* __restrict__ Qf, const float* __restrict__ hp,
    int* __restrict__ buckets, float* __restrict__ rown)
{
    __shared__ float hpl[65 * 6];
    const int tid = threadIdx.x;
    if (tid < 65 * 6) hpl[tid] = hp[tid];
    __syncthreads();

    const int idx = blockIdx.x * 256 + tid;       // 65536 total
    const int m = idx >> 4, h = idx & 15;
    const float4* q4 = (const float4*)(Qf + (size_t)m * 1024 + h * 64);

    float pj[6];
    float nrm = 0.f;
#pragma unroll
    for (int n = 0; n < 6; ++n) pj[n] = hpl[64 * 6 + n];
    for (int d4 = 0; d4 < 16; ++d4) {
        const float4 qv = q4[d4];
        nrm = fmaf(qv.x, qv.x, nrm); nrm = fmaf(qv.y, qv.y, nrm);
        nrm = fmaf(qv.z, qv.z, nrm); nrm = fmaf(qv.w, qv.w, nrm);
#pragma unroll
        for (int n = 0; n < 6; ++n) {
            pj[n] = fmaf(qv.x, hpl[(d4 * 4 + 0) * 6 + n], pj[n]);
            pj[n] = fmaf(qv.y, hpl[(d4 * 4 + 1) * 6 + n], pj[n]);
            pj[n] = fmaf(qv.z, hpl[(d4 * 4 + 2) * 6 + n], pj[n]);
            pj[n] = fmaf(qv.w, hpl[(d4 * 4 + 3) * 6 + n], pj[n]);
        }
    }
    int bkt = 0;
#pragma unroll
    for (int n = 0; n < 6; ++n) bkt |= (pj[n] >= 0.f) << n;
    const int off = ((m >> 11) * 16 + h) * 2048 + (m & 2047);
    buckets[off] = bkt;
    rown[off] = nrm;
}

// ---------------------------------------------------------------------------
// Attention v6 (unchanged from round 8: 100.8us).  Grid (bh=32, qt=16);
// 4 waves; wave owns 32 q-rows (2 ms); K-tile 64 LDS-staged with global-side
// XOR swizzle.  Fixed upper-bound softmax shift (log2e folded); P stored via
// high-half pack; P buffer reused across ms (LDS 33 KB).
// ---------------------------------------------------------------------------
__global__ __launch_bounds__(256, 2) void attn_kernel(
    const unsigned short* __restrict__ Qb, const unsigned short* __restrict__ Qlo,
    const unsigned short* __restrict__ Vt, const int* __restrict__ bks,
    const float* __restrict__ rown, float* __restrict__ out)
{
    __shared__ unsigned short Khi[64 * 64];
    __shared__ unsigned short Klo[64 * 64];
    __shared__ unsigned short Vs[64 * 64];
    __shared__ unsigned short P[4][16 * 64];
    __shared__ float smax[4];

    const int tid = threadIdx.x;
    const int w = tid >> 6, lane = tid & 63;
    const int i = lane & 15, qd = lane >> 4;
    const int l8 = lane >> 3, j = lane & 7;
    const int bh = blockIdx.x;
    const int qbase = blockIdx.y * 128 + w * 32;

    const unsigned short* Qh = Qb + (size_t)bh * 2048 * 64;
    const unsigned short* Ql = Qlo + (size_t)bh * 2048 * 64;
    const unsigned short* Vb = Vt + (size_t)bh * 64 * 2048;
    const int* bk = bks + bh * 2048;
    const float* rnh = rown + bh * 2048;
    unsigned short* Pw = &P[w][0];

    float lm = 0.f;
    for (int t = tid; t < 2048; t += 256) lm = fmaxf(lm, rnh[t]);
#pragma unroll
    for (int msk = 1; msk < 64; msk <<= 1) lm = fmaxf(lm, __shfl_xor(lm, msk));
    if (lane == 0) smax[w] = lm;
    __syncthreads();
    const float sqM = sqrtf(fmaxf(fmaxf(smax[0], smax[1]),
                                  fmaxf(smax[2], smax[3])));

    float m2row[2][4], lrun[2][4];
    int qbr[2][4];
#pragma unroll
    for (int ms = 0; ms < 2; ++ms)
#pragma unroll
        for (int r = 0; r < 4; ++r) {
            const int row = qbase + ms * 16 + qd * 4 + r;
            m2row[ms][r] = 2.84030586f * sqrtf(rnh[row]) * sqM + 0.72134754f;
            qbr[ms][r] = bk[row];
            lrun[ms][r] = 0.f;
        }

    short8 aqh0[2], aqh1[2], aql0[2], aql1[2];
#pragma unroll
    for (int ms = 0; ms < 2; ++ms) {
        const unsigned short* qp = Qh + (size_t)(qbase + ms * 16 + i) * 64 + qd * 8;
        const unsigned short* lp = Ql + (size_t)(qbase + ms * 16 + i) * 64 + qd * 8;
        aqh0[ms] = *(const short8*)qp; aqh1[ms] = *(const short8*)(qp + 32);
        aql0[ms] = *(const short8*)lp; aql1[ms] = *(const short8*)(lp + 32);
    }

    f32x4 o[2][4];
#pragma unroll
    for (int ms = 0; ms < 2; ++ms)
#pragma unroll
        for (int d = 0; d < 4; ++d) o[ms][d] = f32x4{0.f, 0.f, 0.f, 0.f};

    for (int t0 = 0; t0 < 2048; t0 += 64) {
        __syncthreads();
#pragma unroll
        for (int c2 = 0; c2 < 2; ++c2) {
            const int r = w * 16 + c2 * 8 + l8;
            const int swz = ((j ^ l8) << 3);
            glds16(Qh + (size_t)(t0 + r) * 64 + swz, &Khi[w * 1024 + c2 * 512]);
            glds16(Ql + (size_t)(t0 + r) * 64 + swz, &Klo[w * 1024 + c2 * 512]);
            glds16(Vb + (size_t)r * 2048 + t0 + swz, &Vs[w * 1024 + c2 * 512]);
        }
        __syncthreads();

        f32x4 s[2][4];
        int kb[4];
#pragma unroll
        for (int sub = 0; sub < 4; ++sub) {
            const int kr = sub * 16 + i;
            const int sw = i & 7;
            const short8 bh0 = *(const short8*)&Khi[kr * 64 + ((qd ^ sw) << 3)];
            const short8 bh1 = *(const short8*)&Khi[kr * 64 + (((qd + 4) ^ sw) << 3)];
            const short8 bl0 = *(const short8*)&Klo[kr * 64 + ((qd ^ sw) << 3)];
            const short8 bl1 = *(const short8*)&Klo[kr * 64 + (((qd + 4) ^ sw) << 3)];
            kb[sub] = bk[t0 + kr];
#pragma unroll
            for (int ms = 0; ms < 2; ++ms) {
                f32x4 t = f32x4{0.f, 0.f, 0.f, 0.f};
                t = __builtin_amdgcn_mfma_f32_16x16x32_bf16(aqh0[ms], bh0, t, 0, 0, 0);
                t = __builtin_amdgcn_mfma_f32_16x16x32_bf16(aqh1[ms], bh1, t, 0, 0, 0);
                t = __builtin_amdgcn_mfma_f32_16x16x32_bf16(aql0[ms], bh0, t, 0, 0, 0);
                t = __builtin_amdgcn_mfma_f32_16x16x32_bf16(aql1[ms], bh1, t, 0, 0, 0);
                t = __builtin_amdgcn_mfma_f32_16x16x32_bf16(aqh0[ms], bl0, t, 0, 0, 0);
                t = __builtin_amdgcn_mfma_f32_16x16x32_bf16(aqh1[ms], bl1, t, 0, 0, 0);
                s[ms][sub] = t;
            }
        }

        short8 vb0[4], vb1[4];
#pragma unroll
        for (int dsub = 0; dsub < 4; ++dsub) {
            const int dr = dsub * 16 + i;
            const int sw = i & 7;
            vb0[dsub] = *(const short8*)&Vs[dr * 64 + ((qd ^ sw) << 3)];
            vb1[dsub] = *(const short8*)&Vs[dr * 64 + (((qd + 4) ^ sw) << 3)];
        }

#pragma unroll
        for (int ms = 0; ms < 2; ++ms) {
#pragma unroll
            for (int sub = 0; sub < 4; ++sub)
#pragma unroll
                for (int r = 0; r < 4; ++r) {
                    const float c2f = (kb[sub] == qbr[ms][r]) ? 2.84030586f
                                                              : 2.79522164f;
                    const float p = exp2f(fmaf(s[ms][sub][r], c2f, -m2row[ms][r]));
                    lrun[ms][r] += p;
                    const unsigned int pu = __float_as_uint(p);
                    const int row = qd * 4 + r, col = sub * 16 + i;
                    Pw[row * 64 + (((col >> 3) ^ (row & 7)) << 3) + (col & 7)] =
                        (unsigned short)(pu >> 16);
                }
            const short8 pa0 = *(const short8*)&Pw[i * 64 + ((qd ^ (i & 7)) << 3)];
            const short8 pa1 = *(const short8*)&Pw[i * 64 + (((qd + 4) ^ (i & 7)) << 3)];
#pragma unroll
            for (int dsub = 0; dsub < 4; ++dsub) {
                o[ms][dsub] = __builtin_amdgcn_mfma_f32_16x16x32_bf16(
                    pa0, vb0[dsub], o[ms][dsub], 0, 0, 0);
                o[ms][dsub] = __builtin_amdgcn_mfma_f32_16x16x32_bf16(
                    pa1, vb1[dsub], o[ms][dsub], 0, 0, 0);
            }
        }
    }

#pragma unroll
    for (int ms = 0; ms < 2; ++ms)
#pragma unroll
        for (int r = 0; r < 4; ++r) {
#pragma unroll
            for (int msk = 1; msk < 16; msk <<= 1)
                lrun[ms][r] += __shfl_xor(lrun[ms][r], msk);
        }
    const int b = bh >> 4, h = bh & 15;
#pragma unroll
    for (int ms = 0; ms < 2; ++ms)
#pragma unroll
        for (int dsub = 0; dsub < 4; ++dsub)
#pragma unroll
            for (int r = 0; r < 4; ++r) {
                const float v = o[ms][dsub][r] / lrun[ms][r];
                const int srow = qbase + ms * 16 + qd * 4 + r;
                out[((size_t)(b * 2048 + srow)) * 1024 + h * 64 + dsub * 16 + i] = v;
            }
}

// ---------------------------------------------------------------------------
extern "C" void kernel_launch(void* const* d_in, const int* in_sizes, int n_in,
                              void* d_out, int out_size, void* d_ws, size_t ws_size,
                              hipStream_t stream)
{
    const float* x  = (const float*)d_in[0];
    const float* Wq = (const float*)d_in[1];
    const float* bq = (const float*)d_in[2];
    const float* Wv = (const float*)d_in[3];
    const float* bv = (const float*)d_in[4];
    const float* hp = (const float*)d_in[5];
    float* out = (float*)d_out;

    char* ws = (char*)d_ws;
    const size_t MB = (size_t)1 << 20;
    unsigned short* xh  = (unsigned short*)(ws);            // 8 MB
    unsigned short* xl  = (unsigned short*)(ws + 8 * MB);   // 8 MB
    unsigned short* Wqh = (unsigned short*)(ws + 16 * MB);  // 2 MB
    unsigned short* Wql = (unsigned short*)(ws + 18 * MB);  // 2 MB
    unsigned short* Wvh = (unsigned short*)(ws + 20 * MB);  // 2 MB
    unsigned short* Qb  = (unsigned short*)(ws + 22 * MB);  // 8 MB
    unsigned short* Qlo = (unsigned short*)(ws + 30 * MB);  // 8 MB
    unsigned short* Vt  = (unsigned short*)(ws + 38 * MB);  // 8 MB
    float*          Qf  = (float*)(ws + 46 * MB);           // 16 MB
    int*        buckets = (int*)(ws + 62 * MB);             // 256 KB
    float*         rown = (float*)(ws + 62 * MB + 256 * 1024);  // 256 KB

    split_kernel<<<dim3(4096), 256, 0, stream>>>(x, xh, xl, 1048576);
    split_kernel<<<dim3(1024), 256, 0, stream>>>(Wq, Wqh, Wql, 262144);
    split_kernel<<<dim3(1024), 256, 0, stream>>>(Wv, Wvh, nullptr, 262144);

    gemm_qv<<<dim3(1024), 256, 0, stream>>>(xh, xl, Wqh, Wql, Wvh, bq, bv,
                                            Qf, Qb, Qlo, Vt);
    bucket_kernel<<<dim3(256), 256, 0, stream>>>(Qf, hp, buckets, rown);
    attn_kernel<<<dim3(32, 16), 256, 0, stream>>>(Qb, Qlo, Vt, buckets, rown, out);
}

// Round 10
// 228.646 us; speedup vs baseline: 1.0049x; 1.0049x over previous
//
#include <hip/hip_runtime.h>

// ---------------------------------------------------------------------------
// LSH attention, MI355X.  B=2, S=2048, E=1024, H=16, Dh=64, NB=64, NH=6.
// ALL inputs/outputs are FP32.
//   0) split_kernel: fp32 -> bf16 hi (+ optional lo residual)
//   1) gemm_qv v2: 1024 blocks (4/CU), 64x128 tiles, BK=32, LDS-staged.
//      XCD CONTRACT (round-9 evidence: identical attn code ran 100.8us vs
//      114.5us depending only on gemm's write placement): head-pair
//      {2j,2j+1}'s Qb/Qlo/Vt lives on XCD j.  Q path: n0=(blk&7)*128 ->
//      XCD blk%8 = head>>1 (already).  V path REMAPPED: head=2*(b2&7)+
//      ((b2>>3)&1), tok=(b2>>4) -> XCD b2%8 = head>>1.
//   2) bucket_kernel: bucket bits = sign(fp32 q . hyperplanes) + row |q|^2
//   3) attn_kernel v7 = v6 + head swizzle: block x handles h=2*(x&7)+
//      ((x>>4)&1), b=(x>>3)&1 -> runs on XCD x%8 = h>>1 = where its K/V
//      lives; the ~400MB logical K/V re-read becomes local-L2.
// ---------------------------------------------------------------------------

typedef short short8 __attribute__((ext_vector_type(8)));
typedef float f32x4 __attribute__((ext_vector_type(4)));
typedef unsigned short us4 __attribute__((ext_vector_type(4)));

__device__ __forceinline__ float bff(unsigned short h) {
    return __uint_as_float(((unsigned int)h) << 16);
}
__device__ __forceinline__ unsigned short f2bf(float f) {  // RNE, finite inputs
    unsigned int u = __float_as_uint(f);
    u += 0x7fffu + ((u >> 16) & 1u);
    return (unsigned short)(u >> 16);
}

__device__ __forceinline__ void glds16(const unsigned short* g, unsigned short* l) {
    __builtin_amdgcn_global_load_lds(
        (const __attribute__((address_space(1))) unsigned int*)g,
        (__attribute__((address_space(3))) unsigned int*)l, 16, 0, 0);
}

// ---------------------------------------------------------------------------
__global__ __launch_bounds__(256) void split_kernel(
    const float* __restrict__ in, unsigned short* __restrict__ hi,
    unsigned short* __restrict__ lo, int n4)
{
    const int idx = blockIdx.x * 256 + threadIdx.x;
    if (idx >= n4) return;
    const float4 v = ((const float4*)in)[idx];
    us4 h;
    h.x = f2bf(v.x); h.y = f2bf(v.y); h.z = f2bf(v.z); h.w = f2bf(v.w);
    ((us4*)hi)[idx] = h;
    if (lo) {
        us4 l;
        l.x = f2bf(v.x - bff(h.x)); l.y = f2bf(v.y - bff(h.y));
        l.z = f2bf(v.z - bff(h.z)); l.w = f2bf(v.w - bff(h.w));
        ((us4*)lo)[idx] = l;
    }
}

// ---------------------------------------------------------------------------
// Merged projection GEMM v2 + XCD-aligned V mapping.
// ---------------------------------------------------------------------------
__global__ __launch_bounds__(256, 4) void gemm_qv(
    const unsigned short* __restrict__ xh, const unsigned short* __restrict__ xl,
    const unsigned short* __restrict__ wqh, const unsigned short* __restrict__ wql,
    const unsigned short* __restrict__ wvh,
    const float* __restrict__ bq, const float* __restrict__ bv,
    float* __restrict__ Qf, unsigned short* __restrict__ Qb,
    unsigned short* __restrict__ Qlo, unsigned short* __restrict__ Vt)
{
    __shared__ unsigned short Ah[64 * 32], Al[64 * 32];
    __shared__ unsigned short Bh[128 * 32], Bl[128 * 32];

    const int tid = threadIdx.x;
    const int w = tid >> 6, lane = tid & 63;
    const int i = lane & 15, qd = lane >> 4;
    const int srow = lane >> 2, schk = (lane & 3) * 8;  // staging row/chunk
    const int nw = w * 32;
    const int blk = blockIdx.x;
    const bool isq = blk < 512;

    f32x4 acc[4][2];
#pragma unroll
    for (int a = 0; a < 4; ++a)
#pragma unroll
        for (int b2 = 0; b2 < 2; ++b2) acc[a][b2] = f32x4{0.f, 0.f, 0.f, 0.f};

    if (isq) {
        const int m0 = (blk >> 3) * 64;    // token tile (64 rows)
        const int n0 = (blk & 7) * 128;    // channel tile -> XCD = head>>1
        for (int k0 = 0; k0 < 1024; k0 += 32) {
            __syncthreads();
#pragma unroll
            for (int cc = 0; cc < 6; ++cc) {
                const int c = w * 6 + cc;
                if (c < 4) {
                    const int rb = c * 16;
                    glds16(xh + (size_t)(m0 + rb + srow) * 1024 + k0 + schk,
                           &Ah[rb * 32]);
                } else if (c < 8) {
                    const int rb = (c - 4) * 16;
                    glds16(xl + (size_t)(m0 + rb + srow) * 1024 + k0 + schk,
                           &Al[rb * 32]);
                } else if (c < 16) {
                    const int rb = (c - 8) * 16;
                    glds16(wqh + (size_t)(n0 + rb + srow) * 1024 + k0 + schk,
                           &Bh[rb * 32]);
                } else {
                    const int rb = (c - 16) * 16;
                    glds16(wql + (size_t)(n0 + rb + srow) * 1024 + k0 + schk,
                           &Bl[rb * 32]);
                }
            }
            __syncthreads();

            short8 ah[4], al[4], bh2[2], bl2[2];
#pragma unroll
            for (int mm = 0; mm < 4; ++mm) {
                ah[mm] = *(const short8*)&Ah[(mm * 16 + i) * 32 + qd * 8];
                al[mm] = *(const short8*)&Al[(mm * 16 + i) * 32 + qd * 8];
            }
#pragma unroll
            for (int nn = 0; nn < 2; ++nn) {
                bh2[nn] = *(const short8*)&Bh[(nw + nn * 16 + i) * 32 + qd * 8];
                bl2[nn] = *(const short8*)&Bl[(nw + nn * 16 + i) * 32 + qd * 8];
            }
#pragma unroll
            for (int mm = 0; mm < 4; ++mm)
#pragma unroll
                for (int nn = 0; nn < 2; ++nn) {
                    acc[mm][nn] = __builtin_amdgcn_mfma_f32_16x16x32_bf16(
                        ah[mm], bh2[nn], acc[mm][nn], 0, 0, 0);
                    acc[mm][nn] = __builtin_amdgcn_mfma_f32_16x16x32_bf16(
                        al[mm], bh2[nn], acc[mm][nn], 0, 0, 0);
                    acc[mm][nn] = __builtin_amdgcn_mfma_f32_16x16x32_bf16(
                        ah[mm], bl2[nn], acc[mm][nn], 0, 0, 0);
                }
        }
#pragma unroll
        for (int mm = 0; mm < 4; ++mm)
#pragma unroll
            for (int nn = 0; nn < 2; ++nn)
#pragma unroll
                for (int rr = 0; rr < 4; ++rr) {
                    const int row = m0 + mm * 16 + qd * 4 + rr;  // token
                    const int col = n0 + nw + nn * 16 + i;       // channel
                    const float v = acc[mm][nn][rr] + bq[col];
                    Qf[(size_t)row * 1024 + col] = v;
                    const unsigned short hs = f2bf(v);
                    const float lo = v - bff(hs);
                    const int b = row >> 11, s = row & 2047;
                    const int hh = col >> 6, d = col & 63;
                    const size_t oi = ((size_t)((b << 4) + hh) * 2048 + s) * 64 + d;
                    Qb[oi] = hs;
                    Qlo[oi] = f2bf(lo);
                }
    } else {
        const int b2 = blk - 512;
        // XCD-aligned: head = 2*(b2&7)+((b2>>3)&1) -> XCD b2%8 = head>>1
        const int m0 = (2 * (b2 & 7) + ((b2 >> 3) & 1)) * 64;  // channel tile
        const int n0 = (b2 >> 4) * 128;                         // token tile
        for (int k0 = 0; k0 < 1024; k0 += 32) {
            __syncthreads();
#pragma unroll
            for (int cc = 0; cc < 3; ++cc) {
                const int c = w * 3 + cc;
                if (c < 4) {
                    const int rb = c * 16;
                    glds16(wvh + (size_t)(m0 + rb + srow) * 1024 + k0 + schk,
                           &Ah[rb * 32]);
                } else {
                    const int rb = (c - 4) * 16;
                    glds16(xh + (size_t)(n0 + rb + srow) * 1024 + k0 + schk,
                           &Bh[rb * 32]);
                }
            }
            __syncthreads();

            short8 af[4], bf2[2];
#pragma unroll
            for (int mm = 0; mm < 4; ++mm)
                af[mm] = *(const short8*)&Ah[(mm * 16 + i) * 32 + qd * 8];
#pragma unroll
            for (int nn = 0; nn < 2; ++nn)
                bf2[nn] = *(const short8*)&Bh[(nw + nn * 16 + i) * 32 + qd * 8];
#pragma unroll
            for (int mm = 0; mm < 4; ++mm)
#pragma unroll
                for (int nn = 0; nn < 2; ++nn)
                    acc[mm][nn] = __builtin_amdgcn_mfma_f32_16x16x32_bf16(
                        af[mm], bf2[nn], acc[mm][nn], 0, 0, 0);
        }
#pragma unroll
        for (int mm = 0; mm < 4; ++mm)
#pragma unroll
            for (int nn = 0; nn < 2; ++nn)
#pragma unroll
                for (int rr = 0; rr < 4; ++rr) {
                    const int rch = m0 + mm * 16 + qd * 4 + rr;  // channel
                    const int tok = n0 + nw + nn * 16 + i;       // token
                    const float v = acc[mm][nn][rr] + bv[rch];
                    const int b = tok >> 11, s = tok & 2047;
                    Vt[((size_t)(b * 1024 + rch)) * 2048 + s] = f2bf(v);
                }
    }
}

// ---------------------------------------------------------------------------
// Buckets + row norms from fp32 q.  One thread per (token, head), float4.
// ---------------------------------------------------------------------------
__global__ __launch_bounds__(256) void bucket_kernel(
    const float* __restrict__ Qf, const float* __restrict__ hp,
    int* __restrict__ buckets, float* __restrict__ rown)
{
    __shared__ float hpl[65 * 6];
    const int tid = threadIdx.x;
    if (tid < 65 * 6) hpl[tid] = hp[tid];
    __syncthreads();

    const int idx = blockIdx.x * 256 + tid;       // 65536 total
    const int m = idx >> 4, h = idx & 15;
    const float4* q4 = (const float4*)(Qf + (size_t)m * 1024 + h * 64);

    float pj[6];
    float nrm = 0.f;
#pragma unroll
    for (int n = 0; n < 6; ++n) pj[n] = hpl[64 * 6 + n];
    for (int d4 = 0; d4 < 16; ++d4) {
        const float4 qv = q4[d4];
        nrm = fmaf(qv.x, qv.x, nrm); nrm = fmaf(qv.y, qv.y, nrm);
        nrm = fmaf(qv.z, qv.z, nrm); nrm = fmaf(qv.w, qv.w, nrm);
#pragma unroll
        for (int n = 0; n < 6; ++n) {
            pj[n] = fmaf(qv.x, hpl[(d4 * 4 + 0) * 6 + n], pj[n]);
            pj[n] = fmaf(qv.y, hpl[(d4 * 4 + 1) * 6 + n], pj[n]);
            pj[n] = fmaf(qv.z, hpl[(d4 * 4 + 2) * 6 + n], pj[n]);
            pj[n] = fmaf(qv.w, hpl[(d4 * 4 + 3) * 6 + n], pj[n]);
        }
    }
    int bkt = 0;
#pragma unroll
    for (int n = 0; n < 6; ++n) bkt |= (pj[n] >= 0.f) << n;
    const int off = ((m >> 11) * 16 + h) * 2048 + (m & 2047);
    buckets[off] = bkt;
    rown[off] = nrm;
}

// ---------------------------------------------------------------------------
// Attention v7.  Grid (x=32, qt=16); block x -> h = 2*(x&7)+((x>>4)&1),
// b = (x>>3)&1, so XCD x%8 = h>>1 = the XCD whose L2 holds this head's
// Qb/Qlo/Vt (matching gemm_qv's write placement).  Otherwise identical to
// round-8 v6 (100.8us best): 4 waves x 32 q-rows, K-tile 64 LDS-staged,
// fixed upper-bound exp2 softmax, P high-half pack, P reuse across ms.
// ---------------------------------------------------------------------------
__global__ __launch_bounds__(256, 2) void attn_kernel(
    const unsigned short* __restrict__ Qb, const unsigned short* __restrict__ Qlo,
    const unsigned short* __restrict__ Vt, const int* __restrict__ bks,
    const float* __restrict__ rown, float* __restrict__ out)
{
    __shared__ unsigned short Khi[64 * 64];
    __shared__ unsigned short Klo[64 * 64];
    __shared__ unsigned short Vs[64 * 64];
    __shared__ unsigned short P[4][16 * 64];
    __shared__ float smax[4];

    const int tid = threadIdx.x;
    const int w = tid >> 6, lane = tid & 63;
    const int i = lane & 15, qd = lane >> 4;
    const int l8 = lane >> 3, j = lane & 7;
    const int x = blockIdx.x;
    const int h = 2 * (x & 7) + ((x >> 4) & 1);   // XCD x%8 == h>>1
    const int b = (x >> 3) & 1;
    const int bh = b * 16 + h;
    const int qbase = blockIdx.y * 128 + w * 32;

    const unsigned short* Qh = Qb + (size_t)bh * 2048 * 64;
    const unsigned short* Ql = Qlo + (size_t)bh * 2048 * 64;
    const unsigned short* Vb = Vt + (size_t)bh * 64 * 2048;
    const int* bk = bks + bh * 2048;
    const float* rnh = rown + bh * 2048;
    unsigned short* Pw = &P[w][0];

    float lm = 0.f;
    for (int t = tid; t < 2048; t += 256) lm = fmaxf(lm, rnh[t]);
#pragma unroll
    for (int msk = 1; msk < 64; msk <<= 1) lm = fmaxf(lm, __shfl_xor(lm, msk));
    if (lane == 0) smax[w] = lm;
    __syncthreads();
    const float sqM = sqrtf(fmaxf(fmaxf(smax[0], smax[1]),
                                  fmaxf(smax[2], smax[3])));

    float m2row[2][4], lrun[2][4];
    int qbr[2][4];
#pragma unroll
    for (int ms = 0; ms < 2; ++ms)
#pragma unroll
        for (int r = 0; r < 4; ++r) {
            const int row = qbase + ms * 16 + qd * 4 + r;
            m2row[ms][r] = 2.84030586f * sqrtf(rnh[row]) * sqM + 0.72134754f;
            qbr[ms][r] = bk[row];
            lrun[ms][r] = 0.f;
        }

    short8 aqh0[2], aqh1[2], aql0[2], aql1[2];
#pragma unroll
    for (int ms = 0; ms < 2; ++ms) {
        const unsigned short* qp = Qh + (size_t)(qbase + ms * 16 + i) * 64 + qd * 8;
        const unsigned short* lp = Ql + (size_t)(qbase + ms * 16 + i) * 64 + qd * 8;
        aqh0[ms] = *(const short8*)qp; aqh1[ms] = *(const short8*)(qp + 32);
        aql0[ms] = *(const short8*)lp; aql1[ms] = *(const short8*)(lp + 32);
    }

    f32x4 o[2][4];
#pragma unroll
    for (int ms = 0; ms < 2; ++ms)
#pragma unroll
        for (int d = 0; d < 4; ++d) o[ms][d] = f32x4{0.f, 0.f, 0.f, 0.f};

    for (int t0 = 0; t0 < 2048; t0 += 64) {
        __syncthreads();
#pragma unroll
        for (int c2 = 0; c2 < 2; ++c2) {
            const int r = w * 16 + c2 * 8 + l8;
            const int swz = ((j ^ l8) << 3);
            glds16(Qh + (size_t)(t0 + r) * 64 + swz, &Khi[w * 1024 + c2 * 512]);
            glds16(Ql + (size_t)(t0 + r) * 64 + swz, &Klo[w * 1024 + c2 * 512]);
            glds16(Vb + (size_t)r * 2048 + t0 + swz, &Vs[w * 1024 + c2 * 512]);
        }
        __syncthreads();

        f32x4 s[2][4];
        int kb[4];
#pragma unroll
        for (int sub = 0; sub < 4; ++sub) {
            const int kr = sub * 16 + i;
            const int sw = i & 7;
            const short8 bh0 = *(const short8*)&Khi[kr * 64 + ((qd ^ sw) << 3)];
            const short8 bh1 = *(const short8*)&Khi[kr * 64 + (((qd + 4) ^ sw) << 3)];
            const short8 bl0 = *(const short8*)&Klo[kr * 64 + ((qd ^ sw) << 3)];
            const short8 bl1 = *(const short8*)&Klo[kr * 64 + (((qd + 4) ^ sw) << 3)];
            kb[sub] = bk[t0 + kr];
#pragma unroll
            for (int ms = 0; ms < 2; ++ms) {
                f32x4 t = f32x4{0.f, 0.f, 0.f, 0.f};
                t = __builtin_amdgcn_mfma_f32_16x16x32_bf16(aqh0[ms], bh0, t, 0, 0, 0);
                t = __builtin_amdgcn_mfma_f32_16x16x32_bf16(aqh1[ms], bh1, t, 0, 0, 0);
                t = __builtin_amdgcn_mfma_f32_16x16x32_bf16(aql0[ms], bh0, t, 0, 0, 0);
                t = __builtin_amdgcn_mfma_f32_16x16x32_bf16(aql1[ms], bh1, t, 0, 0, 0);
                t = __builtin_amdgcn_mfma_f32_16x16x32_bf16(aqh0[ms], bl0, t, 0, 0, 0);
                t = __builtin_amdgcn_mfma_f32_16x16x32_bf16(aqh1[ms], bl1, t, 0, 0, 0);
                s[ms][sub] = t;
            }
        }

        short8 vb0[4], vb1[4];
#pragma unroll
        for (int dsub = 0; dsub < 4; ++dsub) {
            const int dr = dsub * 16 + i;
            const int sw = i & 7;
            vb0[dsub] = *(const short8*)&Vs[dr * 64 + ((qd ^ sw) << 3)];
            vb1[dsub] = *(const short8*)&Vs[dr * 64 + (((qd + 4) ^ sw) << 3)];
        }

#pragma unroll
        for (int ms = 0; ms < 2; ++ms) {
#pragma unroll
            for (int sub = 0; sub < 4; ++sub)
#pragma unroll
                for (int r = 0; r < 4; ++r) {
                    const float c2f = (kb[sub] == qbr[ms][r]) ? 2.84030586f
                                                              : 2.79522164f;
                    const float p = exp2f(fmaf(s[ms][sub][r], c2f, -m2row[ms][r]));
                    lrun[ms][r] += p;
                    const unsigned int pu = __float_as_uint(p);
                    const int row = qd * 4 + r, col = sub * 16 + i;
                    Pw[row * 64 + (((col >> 3) ^ (row & 7)) << 3) + (col & 7)] =
                        (unsigned short)(pu >> 16);
                }
            const short8 pa0 = *(const short8*)&Pw[i * 64 + ((qd ^ (i & 7)) << 3)];
            const short8 pa1 = *(const short8*)&Pw[i * 64 + (((qd + 4) ^ (i & 7)) << 3)];
#pragma unroll
            for (int dsub = 0; dsub < 4; ++dsub) {
                o[ms][dsub] = __builtin_amdgcn_mfma_f32_16x16x32_bf16(
                    pa0, vb0[dsub], o[ms][dsub], 0, 0, 0);
                o[ms][dsub] = __builtin_amdgcn_mfma_f32_16x16x32_bf16(
                    pa1, vb1[dsub], o[ms][dsub], 0, 0, 0);
            }
        }
    }

#pragma unroll
    for (int ms = 0; ms < 2; ++ms)
#pragma unroll
        for (int r = 0; r < 4; ++r) {
#pragma unroll
            for (int msk = 1; msk < 16; msk <<= 1)
                lrun[ms][r] += __shfl_xor(lrun[ms][r], msk);
        }
#pragma unroll
    for (int ms = 0; ms < 2; ++ms)
#pragma unroll
        for (int dsub = 0; dsub < 4; ++dsub)
#pragma unroll
            for (int r = 0; r < 4; ++r) {
                const float v = o[ms][dsub][r] / lrun[ms][r];
                const int srow = qbase + ms * 16 + qd * 4 + r;
                out[((size_t)(b * 2048 + srow)) * 1024 + h * 64 + dsub * 16 + i] = v;
            }
}

// ---------------------------------------------------------------------------
extern "C" void kernel_launch(void* const* d_in, const int* in_sizes, int n_in,
                              void* d_out, int out_size, void* d_ws, size_t ws_size,
                              hipStream_t stream)
{
    const float* x  = (const float*)d_in[0];
    const float* Wq = (const float*)d_in[1];
    const float* bq = (const float*)d_in[2];
    const float* Wv = (const float*)d_in[3];
    const float* bv = (const float*)d_in[4];
    const float* hp = (const float*)d_in[5];
    float* out = (float*)d_out;

    char* ws = (char*)d_ws;
    const size_t MB = (size_t)1 << 20;
    unsigned short* xh  = (unsigned short*)(ws);            // 8 MB
    unsigned short* xl  = (unsigned short*)(ws + 8 * MB);   // 8 MB
    unsigned short* Wqh = (unsigned short*)(ws + 16 * MB);  // 2 MB
    unsigned short* Wql = (unsigned short*)(ws + 18 * MB);  // 2 MB
    unsigned short* Wvh = (unsigned short*)(ws + 20 * MB);  // 2 MB
    unsigned short* Qb  = (unsigned short*)(ws + 22 * MB);  // 8 MB
    unsigned short* Qlo = (unsigned short*)(ws + 30 * MB);  // 8 MB
    unsigned short* Vt  = (unsigned short*)(ws + 38 * MB);  // 8 MB
    float*          Qf  = (float*)(ws + 46 * MB);           // 16 MB
    int*        buckets = (int*)(ws + 62 * MB);             // 256 KB
    float*         rown = (float*)(ws + 62 * MB + 256 * 1024);  // 256 KB

    split_kernel<<<dim3(4096), 256, 0, stream>>>(x, xh, xl, 1048576);
    split_kernel<<<dim3(1024), 256, 0, stream>>>(Wq, Wqh, Wql, 262144);
    split_kernel<<<dim3(1024), 256, 0, stream>>>(Wv, Wvh, nullptr, 262144);

    gemm_qv<<<dim3(1024), 256, 0, stream>>>(xh, xl, Wqh, Wql, Wvh, bq, bv,
                                            Qf, Qb, Qlo, Vt);
    bucket_kernel<<<dim3(256), 256, 0, stream>>>(Qf, hp, buckets, rown);
    attn_kernel<<<dim3(32, 16), 256, 0, stream>>>(Qb, Qlo, Vt, buckets, rown, out);
}

// Round 11
// 218.489 us; speedup vs baseline: 1.0517x; 1.0465x over previous
//
#include <hip/hip_runtime.h>

// ---------------------------------------------------------------------------
// LSH attention, MI355X.  B=2, S=2048, E=1024, H=16, Dh=64, NB=64, NH=6.
// ALL inputs/outputs are FP32.
// CONSOLIDATION ROUND: revert to the round-8 best-measured configuration
// (total 222.7us) after R9/R10's gemm restructure + XCD swizzles proved
// net-negative (attn slowed 100.8 -> 114.5/110.4 with identical FETCH;
// placement mechanism not controllable from source).  Single fused split
// launch replaces the three split launches (only change vs R8).
//   0) split_all: x -> xh+xl, Wq -> Wqh+Wql, Wv -> Wvh in ONE launch
//   1) gemm_qv (R8): 512 blocks, 128x128, BK=64, LDS-staged via
//      global_load_lds(16B) + global-side XOR swizzle.
//   2) bucket_kernel: bucket bits = sign(fp32 q . hyperplanes) + row |q|^2
//   3) attn_kernel (R8 v6, 100.8us): grid (bh=32, qt=16), 4 waves x 32
//      q-rows, K-tile 64 LDS-staged, fixed upper-bound exp2 softmax,
//      P high-half pack, P buffer reused across m-subtiles.
// ---------------------------------------------------------------------------

typedef short short8 __attribute__((ext_vector_type(8)));
typedef float f32x4 __attribute__((ext_vector_type(4)));
typedef unsigned short us4 __attribute__((ext_vector_type(4)));

__device__ __forceinline__ float bff(unsigned short h) {
    return __uint_as_float(((unsigned int)h) << 16);
}
__device__ __forceinline__ unsigned short f2bf(float f) {  // RNE, finite inputs
    unsigned int u = __float_as_uint(f);
    u += 0x7fffu + ((u >> 16) & 1u);
    return (unsigned short)(u >> 16);
}

__device__ __forceinline__ void glds16(const unsigned short* g, unsigned short* l) {
    __builtin_amdgcn_global_load_lds(
        (const __attribute__((address_space(1))) unsigned int*)g,
        (__attribute__((address_space(3))) unsigned int*)l, 16, 0, 0);
}

// ---------------------------------------------------------------------------
// Fused split: blk<4096 -> x (hi+lo); <5120 -> Wq (hi+lo); else Wv (hi).
// ---------------------------------------------------------------------------
__global__ __launch_bounds__(256) void split_all(
    const float* __restrict__ x, const float* __restrict__ Wq,
    const float* __restrict__ Wv,
    unsigned short* __restrict__ xh, unsigned short* __restrict__ xl,
    unsigned short* __restrict__ Wqh, unsigned short* __restrict__ Wql,
    unsigned short* __restrict__ Wvh)
{
    const int blk = blockIdx.x;
    const float* in;
    unsigned short *hi, *lo;
    int idx;
    if (blk < 4096) {
        idx = blk * 256 + threadIdx.x; in = x; hi = xh; lo = xl;
    } else if (blk < 5120) {
        idx = (blk - 4096) * 256 + threadIdx.x; in = Wq; hi = Wqh; lo = Wql;
    } else {
        idx = (blk - 5120) * 256 + threadIdx.x; in = Wv; hi = Wvh; lo = nullptr;
    }
    const float4 v = ((const float4*)in)[idx];
    us4 h;
    h.x = f2bf(v.x); h.y = f2bf(v.y); h.z = f2bf(v.z); h.w = f2bf(v.w);
    ((us4*)hi)[idx] = h;
    if (lo) {
        us4 l;
        l.x = f2bf(v.x - bff(h.x)); l.y = f2bf(v.y - bff(h.y));
        l.z = f2bf(v.z - bff(h.z)); l.w = f2bf(v.w - bff(h.w));
        ((us4*)lo)[idx] = l;
    }
}

// ---------------------------------------------------------------------------
// Merged projection GEMM (exact round-8 version).  512 blocks: b<256 Q path
// (m0 token-tile, n0 channel-tile, 3-term hi/lo); b>=256 V path (m0 channel,
// n0 token, 1-term).  128x128 tile, BK=64, LDS staged with global-side XOR
// swizzle; fragment reads apply the inverse -> 2-way LDS conflicts (free).
// ---------------------------------------------------------------------------
__global__ __launch_bounds__(256, 1) void gemm_qv(
    const unsigned short* __restrict__ xh, const unsigned short* __restrict__ xl,
    const unsigned short* __restrict__ wqh, const unsigned short* __restrict__ wql,
    const unsigned short* __restrict__ wvh,
    const float* __restrict__ bq, const float* __restrict__ bv,
    float* __restrict__ Qf, unsigned short* __restrict__ Qb,
    unsigned short* __restrict__ Qlo, unsigned short* __restrict__ Vt)
{
    __shared__ unsigned short Ah[128 * 64], Al[128 * 64];
    __shared__ unsigned short Bh[128 * 64], Bl[128 * 64];

    const int tid = threadIdx.x;
    const int w = tid >> 6, lane = tid & 63;
    const int i = lane & 15, qd = lane >> 4;
    const int l8 = lane >> 3, j = lane & 7;
    const int nw = w * 32;
    const int blk = blockIdx.x;
    const bool isq = blk < 256;

    f32x4 acc[8][2];
#pragma unroll
    for (int a = 0; a < 8; ++a)
#pragma unroll
        for (int b2 = 0; b2 < 2; ++b2) acc[a][b2] = f32x4{0.f, 0.f, 0.f, 0.f};

    const int gro = ((j ^ l8) << 3);

    if (isq) {
        const int m0 = (blk >> 3) * 128;   // token tile
        const int n0 = (blk & 7) * 128;    // channel tile
        for (int k0 = 0; k0 < 1024; k0 += 64) {
            __syncthreads();
#pragma unroll
            for (int c = 0; c < 4; ++c) {
                const int r = w * 32 + c * 8;
                const size_t gx = (size_t)(m0 + r + l8) * 1024 + k0 + gro;
                const size_t gw = (size_t)(n0 + r + l8) * 1024 + k0 + gro;
                glds16(xh + gx, &Ah[r * 64]);
                glds16(xl + gx, &Al[r * 64]);
                glds16(wqh + gw, &Bh[r * 64]);
                glds16(wql + gw, &Bl[r * 64]);
            }
            __syncthreads();
#pragma unroll
            for (int kc = 0; kc < 2; ++kc) {
                const int ch = (((kc * 4 + qd) ^ (i & 7)) << 3);
                short8 ah[8], al[8], bh2[2], bl2[2];
#pragma unroll
                for (int mm = 0; mm < 8; ++mm) {
                    ah[mm] = *(const short8*)&Ah[(mm * 16 + i) * 64 + ch];
                    al[mm] = *(const short8*)&Al[(mm * 16 + i) * 64 + ch];
                }
#pragma unroll
                for (int nn = 0; nn < 2; ++nn) {
                    bh2[nn] = *(const short8*)&Bh[(nw + nn * 16 + i) * 64 + ch];
                    bl2[nn] = *(const short8*)&Bl[(nw + nn * 16 + i) * 64 + ch];
                }
#pragma unroll
                for (int mm = 0; mm < 8; ++mm)
#pragma unroll
                    for (int nn = 0; nn < 2; ++nn) {
                        acc[mm][nn] = __builtin_amdgcn_mfma_f32_16x16x32_bf16(
                            ah[mm], bh2[nn], acc[mm][nn], 0, 0, 0);
                        acc[mm][nn] = __builtin_amdgcn_mfma_f32_16x16x32_bf16(
                            al[mm], bh2[nn], acc[mm][nn], 0, 0, 0);
                        acc[mm][nn] = __builtin_amdgcn_mfma_f32_16x16x32_bf16(
                            ah[mm], bl2[nn], acc[mm][nn], 0, 0, 0);
                    }
            }
        }
#pragma unroll
        for (int mm = 0; mm < 8; ++mm)
#pragma unroll
            for (int nn = 0; nn < 2; ++nn)
#pragma unroll
                for (int rr = 0; rr < 4; ++rr) {
                    const int row = m0 + mm * 16 + qd * 4 + rr;  // token
                    const int col = n0 + nw + nn * 16 + i;       // channel
                    const float v = acc[mm][nn][rr] + bq[col];
                    Qf[(size_t)row * 1024 + col] = v;
                    const unsigned short hs = f2bf(v);
                    const float lo = v - bff(hs);
                    const int b = row >> 11, s = row & 2047;
                    const int hh = col >> 6, d = col & 63;
                    const size_t oi = ((size_t)((b << 4) + hh) * 2048 + s) * 64 + d;
                    Qb[oi] = hs;
                    Qlo[oi] = f2bf(lo);
                }
    } else {
        const int b2 = blk - 256;
        const int m0 = (b2 & 7) * 128;     // channel tile
        const int n0 = (b2 >> 3) * 128;    // token tile
        for (int k0 = 0; k0 < 1024; k0 += 64) {
            __syncthreads();
#pragma unroll
            for (int c = 0; c < 4; ++c) {
                const int r = w * 32 + c * 8;
                glds16(wvh + (size_t)(m0 + r + l8) * 1024 + k0 + gro, &Ah[r * 64]);
                glds16(xh + (size_t)(n0 + r + l8) * 1024 + k0 + gro, &Bh[r * 64]);
            }
            __syncthreads();
#pragma unroll
            for (int kc = 0; kc < 2; ++kc) {
                const int ch = (((kc * 4 + qd) ^ (i & 7)) << 3);
                short8 af[8], bf2[2];
#pragma unroll
                for (int mm = 0; mm < 8; ++mm)
                    af[mm] = *(const short8*)&Ah[(mm * 16 + i) * 64 + ch];
#pragma unroll
                for (int nn = 0; nn < 2; ++nn)
                    bf2[nn] = *(const short8*)&Bh[(nw + nn * 16 + i) * 64 + ch];
#pragma unroll
                for (int mm = 0; mm < 8; ++mm)
#pragma unroll
                    for (int nn = 0; nn < 2; ++nn)
                        acc[mm][nn] = __builtin_amdgcn_mfma_f32_16x16x32_bf16(
                            af[mm], bf2[nn], acc[mm][nn], 0, 0, 0);
            }
        }
#pragma unroll
        for (int mm = 0; mm < 8; ++mm)
#pragma unroll
            for (int nn = 0; nn < 2; ++nn)
#pragma unroll
                for (int rr = 0; rr < 4; ++rr) {
                    const int rch = m0 + mm * 16 + qd * 4 + rr;  // channel
                    const int tok = n0 + nw + nn * 16 + i;       // token
                    const float v = acc[mm][nn][rr] + bv[rch];
                    const int b = tok >> 11, s = tok & 2047;
                    Vt[((size_t)(b * 1024 + rch)) * 2048 + s] = f2bf(v);
                }
    }
}

// ---------------------------------------------------------------------------
// Buckets + row norms from fp32 q.  One thread per (token, head), float4.
// ---------------------------------------------------------------------------
__global__ __launch_bounds__(256) void bucket_kernel(
    const float* __restrict__ Qf, const float* __restrict__ hp,
    int* __restrict__ buckets, float* __restrict__ rown)
{
    __shared__ float hpl[65 * 6];
    const int tid = threadIdx.x;
    if (tid < 65 * 6) hpl[tid] = hp[tid];
    __syncthreads();

    const int idx = blockIdx.x * 256 + tid;       // 65536 total
    const int m = idx >> 4, h = idx & 15;
    const float4* q4 = (const float4*)(Qf + (size_t)m * 1024 + h * 64);

    float pj[6];
    float nrm = 0.f;
#pragma unroll
    for (int n = 0; n < 6; ++n) pj[n] = hpl[64 * 6 + n];
    for (int d4 = 0; d4 < 16; ++d4) {
        const float4 qv = q4[d4];
        nrm = fmaf(qv.x, qv.x, nrm); nrm = fmaf(qv.y, qv.y, nrm);
        nrm = fmaf(qv.z, qv.z, nrm); nrm = fmaf(qv.w, qv.w, nrm);
#pragma unroll
        for (int n = 0; n < 6; ++n) {
            pj[n] = fmaf(qv.x, hpl[(d4 * 4 + 0) * 6 + n], pj[n]);
            pj[n] = fmaf(qv.y, hpl[(d4 * 4 + 1) * 6 + n], pj[n]);
            pj[n] = fmaf(qv.z, hpl[(d4 * 4 + 2) * 6 + n], pj[n]);
            pj[n] = fmaf(qv.w, hpl[(d4 * 4 + 3) * 6 + n], pj[n]);
        }
    }
    int bkt = 0;
#pragma unroll
    for (int n = 0; n < 6; ++n) bkt |= (pj[n] >= 0.f) << n;
    const int off = ((m >> 11) * 16 + h) * 2048 + (m & 2047);
    buckets[off] = bkt;
    rown[off] = nrm;
}

// ---------------------------------------------------------------------------
// Attention (exact round-8 v6, 100.8us).  Grid (bh=32, qt=16); 4 waves;
// wave owns 32 q-rows (2 ms); K-tile 64 LDS-staged with global-side XOR
// swizzle.  Fixed upper-bound softmax shift (log2e folded); P stored via
// high-half pack; P buffer reused across ms (LDS 33 KB).
// ---------------------------------------------------------------------------
__global__ __launch_bounds__(256, 2) void attn_kernel(
    const unsigned short* __restrict__ Qb, const unsigned short* __restrict__ Qlo,
    const unsigned short* __restrict__ Vt, const int* __restrict__ bks,
    const float* __restrict__ rown, float* __restrict__ out)
{
    __shared__ unsigned short Khi[64 * 64];
    __shared__ unsigned short Klo[64 * 64];
    __shared__ unsigned short Vs[64 * 64];
    __shared__ unsigned short P[4][16 * 64];
    __shared__ float smax[4];

    const int tid = threadIdx.x;
    const int w = tid >> 6, lane = tid & 63;
    const int i = lane & 15, qd = lane >> 4;
    const int l8 = lane >> 3, j = lane & 7;
    const int bh = blockIdx.x;
    const int qbase = blockIdx.y * 128 + w * 32;

    const unsigned short* Qh = Qb + (size_t)bh * 2048 * 64;
    const unsigned short* Ql = Qlo + (size_t)bh * 2048 * 64;
    const unsigned short* Vb = Vt + (size_t)bh * 64 * 2048;
    const int* bk = bks + bh * 2048;
    const float* rnh = rown + bh * 2048;
    unsigned short* Pw = &P[w][0];

    float lm = 0.f;
    for (int t = tid; t < 2048; t += 256) lm = fmaxf(lm, rnh[t]);
#pragma unroll
    for (int msk = 1; msk < 64; msk <<= 1) lm = fmaxf(lm, __shfl_xor(lm, msk));
    if (lane == 0) smax[w] = lm;
    __syncthreads();
    const float sqM = sqrtf(fmaxf(fmaxf(smax[0], smax[1]),
                                  fmaxf(smax[2], smax[3])));

    float m2row[2][4], lrun[2][4];
    int qbr[2][4];
#pragma unroll
    for (int ms = 0; ms < 2; ++ms)
#pragma unroll
        for (int r = 0; r < 4; ++r) {
            const int row = qbase + ms * 16 + qd * 4 + r;
            m2row[ms][r] = 2.84030586f * sqrtf(rnh[row]) * sqM + 0.72134754f;
            qbr[ms][r] = bk[row];
            lrun[ms][r] = 0.f;
        }

    short8 aqh0[2], aqh1[2], aql0[2], aql1[2];
#pragma unroll
    for (int ms = 0; ms < 2; ++ms) {
        const unsigned short* qp = Qh + (size_t)(qbase + ms * 16 + i) * 64 + qd * 8;
        const unsigned short* lp = Ql + (size_t)(qbase + ms * 16 + i) * 64 + qd * 8;
        aqh0[ms] = *(const short8*)qp; aqh1[ms] = *(const short8*)(qp + 32);
        aql0[ms] = *(const short8*)lp; aql1[ms] = *(const short8*)(lp + 32);
    }

    f32x4 o[2][4];
#pragma unroll
    for (int ms = 0; ms < 2; ++ms)
#pragma unroll
        for (int d = 0; d < 4; ++d) o[ms][d] = f32x4{0.f, 0.f, 0.f, 0.f};

    for (int t0 = 0; t0 < 2048; t0 += 64) {
        __syncthreads();
#pragma unroll
        for (int c2 = 0; c2 < 2; ++c2) {
            const int r = w * 16 + c2 * 8 + l8;
            const int swz = ((j ^ l8) << 3);
            glds16(Qh + (size_t)(t0 + r) * 64 + swz, &Khi[w * 1024 + c2 * 512]);
            glds16(Ql + (size_t)(t0 + r) * 64 + swz, &Klo[w * 1024 + c2 * 512]);
            glds16(Vb + (size_t)r * 2048 + t0 + swz, &Vs[w * 1024 + c2 * 512]);
        }
        __syncthreads();

        f32x4 s[2][4];
        int kb[4];
#pragma unroll
        for (int sub = 0; sub < 4; ++sub) {
            const int kr = sub * 16 + i;
            const int sw = i & 7;
            const short8 bh0 = *(const short8*)&Khi[kr * 64 + ((qd ^ sw) << 3)];
            const short8 bh1 = *(const short8*)&Khi[kr * 64 + (((qd + 4) ^ sw) << 3)];
            const short8 bl0 = *(const short8*)&Klo[kr * 64 + ((qd ^ sw) << 3)];
            const short8 bl1 = *(const short8*)&Klo[kr * 64 + (((qd + 4) ^ sw) << 3)];
            kb[sub] = bk[t0 + kr];
#pragma unroll
            for (int ms = 0; ms < 2; ++ms) {
                f32x4 t = f32x4{0.f, 0.f, 0.f, 0.f};
                t = __builtin_amdgcn_mfma_f32_16x16x32_bf16(aqh0[ms], bh0, t, 0, 0, 0);
                t = __builtin_amdgcn_mfma_f32_16x16x32_bf16(aqh1[ms], bh1, t, 0, 0, 0);
                t = __builtin_amdgcn_mfma_f32_16x16x32_bf16(aql0[ms], bh0, t, 0, 0, 0);
                t = __builtin_amdgcn_mfma_f32_16x16x32_bf16(aql1[ms], bh1, t, 0, 0, 0);
                t = __builtin_amdgcn_mfma_f32_16x16x32_bf16(aqh0[ms], bl0, t, 0, 0, 0);
                t = __builtin_amdgcn_mfma_f32_16x16x32_bf16(aqh1[ms], bl1, t, 0, 0, 0);
                s[ms][sub] = t;
            }
        }

        short8 vb0[4], vb1[4];
#pragma unroll
        for (int dsub = 0; dsub < 4; ++dsub) {
            const int dr = dsub * 16 + i;
            const int sw = i & 7;
            vb0[dsub] = *(const short8*)&Vs[dr * 64 + ((qd ^ sw) << 3)];
            vb1[dsub] = *(const short8*)&Vs[dr * 64 + (((qd + 4) ^ sw) << 3)];
        }

#pragma unroll
        for (int ms = 0; ms < 2; ++ms) {
#pragma unroll
            for (int sub = 0; sub < 4; ++sub)
#pragma unroll
                for (int r = 0; r < 4; ++r) {
                    const float c2f = (kb[sub] == qbr[ms][r]) ? 2.84030586f
                                                              : 2.79522164f;
                    const float p = exp2f(fmaf(s[ms][sub][r], c2f, -m2row[ms][r]));
                    lrun[ms][r] += p;
                    const unsigned int pu = __float_as_uint(p);
                    const int row = qd * 4 + r, col = sub * 16 + i;
                    Pw[row * 64 + (((col >> 3) ^ (row & 7)) << 3) + (col & 7)] =
                        (unsigned short)(pu >> 16);
                }
            const short8 pa0 = *(const short8*)&Pw[i * 64 + ((qd ^ (i & 7)) << 3)];
            const short8 pa1 = *(const short8*)&Pw[i * 64 + (((qd + 4) ^ (i & 7)) << 3)];
#pragma unroll
            for (int dsub = 0; dsub < 4; ++dsub) {
                o[ms][dsub] = __builtin_amdgcn_mfma_f32_16x16x32_bf16(
                    pa0, vb0[dsub], o[ms][dsub], 0, 0, 0);
                o[ms][dsub] = __builtin_amdgcn_mfma_f32_16x16x32_bf16(
                    pa1, vb1[dsub], o[ms][dsub], 0, 0, 0);
            }
        }
    }

#pragma unroll
    for (int ms = 0; ms < 2; ++ms)
#pragma unroll
        for (int r = 0; r < 4; ++r) {
#pragma unroll
            for (int msk = 1; msk < 16; msk <<= 1)
                lrun[ms][r] += __shfl_xor(lrun[ms][r], msk);
        }
    const int b = bh >> 4, h = bh & 15;
#pragma unroll
    for (int ms = 0; ms < 2; ++ms)
#pragma unroll
        for (int dsub = 0; dsub < 4; ++dsub)
#pragma unroll
            for (int r = 0; r < 4; ++r) {
                const float v = o[ms][dsub][r] / lrun[ms][r];
                const int srow = qbase + ms * 16 + qd * 4 + r;
                out[((size_t)(b * 2048 + srow)) * 1024 + h * 64 + dsub * 16 + i] = v;
            }
}

// ---------------------------------------------------------------------------
extern "C" void kernel_launch(void* const* d_in, const int* in_sizes, int n_in,
                              void* d_out, int out_size, void* d_ws, size_t ws_size,
                              hipStream_t stream)
{
    const float* x  = (const float*)d_in[0];
    const float* Wq = (const float*)d_in[1];
    const float* bq = (const float*)d_in[2];
    const float* Wv = (const float*)d_in[3];
    const float* bv = (const float*)d_in[4];
    const float* hp = (const float*)d_in[5];
    float* out = (float*)d_out;

    char* ws = (char*)d_ws;
    const size_t MB = (size_t)1 << 20;
    unsigned short* xh  = (unsigned short*)(ws);            // 8 MB
    unsigned short* xl  = (unsigned short*)(ws + 8 * MB);   // 8 MB
    unsigned short* Wqh = (unsigned short*)(ws + 16 * MB);  // 2 MB
    unsigned short* Wql = (unsigned short*)(ws + 18 * MB);  // 2 MB
    unsigned short* Wvh = (unsigned short*)(ws + 20 * MB);  // 2 MB
    unsigned short* Qb  = (unsigned short*)(ws + 22 * MB);  // 8 MB
    unsigned short* Qlo = (unsigned short*)(ws + 30 * MB);  // 8 MB
    unsigned short* Vt  = (unsigned short*)(ws + 38 * MB);  // 8 MB
    float*          Qf  = (float*)(ws + 46 * MB);           // 16 MB
    int*        buckets = (int*)(ws + 62 * MB);             // 256 KB
    float*         rown = (float*)(ws + 62 * MB + 256 * 1024);  // 256 KB

    split_all<<<dim3(6144), 256, 0, stream>>>(x, Wq, Wv, xh, xl, Wqh, Wql, Wvh);
    gemm_qv<<<dim3(512), 256, 0, stream>>>(xh, xl, Wqh, Wql, Wvh, bq, bv,
                                           Qf, Qb, Qlo, Vt);
    bucket_kernel<<<dim3(256), 256, 0, stream>>>(Qf, hp, buckets, rown);
    attn_kernel<<<dim3(32, 16), 256, 0, stream>>>(Qb, Qlo, Vt, buckets, rown, out);
}